// Round 8
// baseline (31197.513 us; speedup 1.0000x reference)
//
#include <hip/hip_runtime.h>
#include <hip/hip_bf16.h>
#include <hip/hip_cooperative_groups.h>

namespace cg = cooperative_groups;

typedef __bf16 bf16;
typedef __bf16 bf16x8 __attribute__((ext_vector_type(8)));
typedef float  floatx4 __attribute__((ext_vector_type(4)));
typedef unsigned int uint32;

#define NB   64      // batch
#define NT   240     // timesteps
#define NDIM 512     // audio feature dim
#define NU   1024    // LSTM units
#define NOUT 75      // motion dim
#define NWG  256
#define NTHR 1024

// ring slot strides (elements)
#define HSLOT (64 * 1024)
#define YW    80
#define YSLOT (64 * YW)
#define BW    528
#define BSLOT (64 * BW)

struct Params {
  const float* curr;      // [64,75]
  const float* bias[8];   // enc1,enc2,enc3,fc,dec1,dec2,dec3,out
  const bf16*  pk[8];     // packed weights (B-fragment layout)
  const bf16*  audio_bf;  // [64, 240*512] bf16
  bf16* hr[6];            // h rings [R][64][1024] (enc1..3, dec1..3)
  bf16* ybuf;             // [R][64][80]  (y feedback, cols 75..79 zero)
  bf16* hbot;             // [R][64][528] (_h bottleneck, cols 512..527 zeroed)
  uint32* arrv;           // [256*32] arrival flags (128B spaced)
  uint32* gof;            // (unused, kept for layout)
  float* out;             // [64,240,75]
  int rmask;              // ring depth - 1
  int pmask;              // heavy-sync period - 1
};

__device__ __forceinline__ float sigmoidf_(float x) { return 1.f / (1.f + __expf(-x)); }

// ---- single-hop grid barrier over 256 WGs ----
// Every WG posts its own 128B flag line; threads 0..255 each poll one line.
// Backoff after 4 fast polls to limit fabric storm at 256-WG scale.
__device__ __forceinline__ void gbar(uint32* arrv, uint32 sc, int bid, int tid)
{
  asm volatile("s_waitcnt vmcnt(0)" ::: "memory");
  __syncthreads();
  if (tid == 0)
    __hip_atomic_store(&arrv[bid * 32], sc, __ATOMIC_RELAXED, __HIP_MEMORY_SCOPE_AGENT);
  if (tid < NWG) {
    int spin = 0;
    while (__hip_atomic_load(&arrv[tid * 32], __ATOMIC_RELAXED, __HIP_MEMORY_SCOPE_AGENT) < sc) {
      if (spin < 4) __builtin_amdgcn_s_sleep(1);
      else          __builtin_amdgcn_s_sleep(16);
      if (++spin > (1 << 22)) break;  // bail instead of hard hang
    }
  }
  __syncthreads();
}

// One LSTM cell stage, per-wave self-paced DMA pipeline (NO intra-loop barrier).
// A = [p0 (B1) | p1 (B2-B1) | p2 (KTOT-B2)], widths mult of 8.
// WG (r,w): rows 16r..16r+15, units 16w..16w+15. 16 waves = 4 gates (g=wid&3)
// x 4 K-splits (s=wid>>2). Wave (g,s) processes k-blocks {s, s+4, ...}: per
// k-block it DMAs its OWN 1KB A-frag + 1KB B-frag into a private 4-slot LDS
// ring (3 pairs in flight, counted vmcnt). No cross-wave LDS sharing -> no
// s_barrier stragglers; waves free-run. K-partials reduced via zbuf at the end.
template<int ST0, int B1, int ST1, int B2, int ST2, int KTOT, int KREAL>
__device__ void lstm_cell(const bf16* __restrict__ p0, const bf16* __restrict__ p1,
                          const bf16* __restrict__ p2,
                          const bf16* __restrict__ pack, const float* __restrict__ bias,
                          bf16* __restrict__ hout, float& ccr,
                          float (* __restrict__ zbuf)[64][16], bf16 (* __restrict__ hstage)[16],
                          char* __restrict__ cbuf,
                          int w, int R0, int tid)
{
  const int lane = tid & 63, wid = tid >> 6;
  const int g = wid & 3, s = wid >> 2;
  const int lq = lane >> 4, lr = lane & 15;
  constexpr int NKB = KTOT / 32;      // mult of 4 for all stages (48/64/52)
  constexpr int NITER = NKB / 4;      // k-blocks per wave (12/16/13)

  char* cb = cbuf + (size_t)wid * 8192;   // private 4-slot ring, 2KB/slot

  // per-lane A segment bases (row = R0 + lr), B base (col = 1024g + 16w + lr)
  const bf16* a0 = p0 + (size_t)(R0 + lr) * ST0;
  const bf16* a1 = p1 + (size_t)(R0 + lr) * ST1 - B1;
  const bf16* a2 = p2 + (size_t)(R0 + lr) * ST2 - B2;
  const bf16* bb = pack + ((size_t)lq * 4096 + 1024 * g + 16 * w + lr) * 8;

  auto issue = [&](int i) {
    const int kb = 4 * i + s;
    char* base = cb + (size_t)(i & 3) * 2048;
    int kq = kb * 32 + lq * 8;
    if constexpr (KREAL < KTOT) { if (kq >= KREAL) kq = B2; }  // tail: safe addr x 0-weight
    const bf16* asrc = (kq < B1) ? (a0 + kq) : ((kq < B2) ? (a1 + kq) : (a2 + kq));
    __builtin_amdgcn_global_load_lds((const uint32*)asrc, (uint32*)base, 16, 0, 0);
    const bf16* bsrc = bb + (size_t)kb * (4 * 4096 * 8);
    __builtin_amdgcn_global_load_lds((const uint32*)bsrc, (uint32*)(base + 1024), 16, 0, 0);
  };

  floatx4 c = {0.f, 0.f, 0.f, 0.f};
  auto compute = [&](int i) {
    const char* base = cb + (size_t)(i & 3) * 2048;
    bf16x8 af = *(const bf16x8*)(base + lane * 16);
    bf16x8 bf_ = *(const bf16x8*)(base + 1024 + lane * 16);
    c = __builtin_amdgcn_mfma_f32_16x16x32_bf16(af, bf_, c, 0, 0, 0);
  };

  // entered post-gbar: vmcnt==0 for this wave
  issue(0); issue(1); issue(2);
  int i = 0;
  for (; i + 3 < NITER; ++i) {
    asm volatile("s_waitcnt vmcnt(4)" ::: "memory");  // own pair i landed
    issue(i + 3);                                     // slot (i+3)&3: read at round i-1
    compute(i);
  }
  asm volatile("s_waitcnt vmcnt(4)" ::: "memory"); compute(i); ++i;
  asm volatile("s_waitcnt vmcnt(2)" ::: "memory"); compute(i); ++i;
  asm volatile("s_waitcnt vmcnt(0)" ::: "memory"); compute(i);

  // K-partial -> zbuf[s][g*16 + row][col]  (C/D: col=lane&15, row=lq*4+rr)
  #pragma unroll
  for (int rr = 0; rr < 4; ++rr)
    zbuf[s][g * 16 + lq * 4 + rr][lr] = c[rr];
  __syncthreads();
  // pointwise: 256 threads = 16 rows x 16 units; c-state in per-thread reg
  if (tid < 256) {
    const int m = tid >> 4, u = tid & 15;
    const int uc = 16 * w + u;
    const float zi = zbuf[0][m][u]      + zbuf[1][m][u]      + zbuf[2][m][u]      + zbuf[3][m][u]      + bias[uc];
    const float zf = zbuf[0][16 + m][u] + zbuf[1][16 + m][u] + zbuf[2][16 + m][u] + zbuf[3][16 + m][u] + bias[NU + uc];
    const float zg = zbuf[0][32 + m][u] + zbuf[1][32 + m][u] + zbuf[2][32 + m][u] + zbuf[3][32 + m][u] + bias[2 * NU + uc];
    const float zo = zbuf[0][48 + m][u] + zbuf[1][48 + m][u] + zbuf[2][48 + m][u] + zbuf[3][48 + m][u] + bias[3 * NU + uc];
    const float cold = ccr;
    const float cn = sigmoidf_(zf) * cold + sigmoidf_(zi) * tanhf(zg);
    ccr = cn;
    hstage[m][u] = (bf16)(sigmoidf_(zo) * tanhf(cn));
  }
  __syncthreads();
  // agent-scope dword stores of this WG's 16x16 h block
  if (tid < 128) {
    const int m = tid >> 3, up = tid & 7;
    const uint32 vv = *(const uint32*)&hstage[m][2 * up];
    __hip_atomic_store((uint32*)(hout + (size_t)(R0 + m) * NU + 16 * w) + up, vv,
                       __ATOMIC_RELAXED, __HIP_MEMORY_SCOPE_AGENT);
  }
}

// Small GEMM (fc / out): z[64,NEFF] = A[64,1024] @ pack. 16 waves: v=wid&3 rows, s=wid>>2 K.
// 8 k-blocks/wave: weights preloaded, A 2-deep pipelined (small enough for regs).
template<int NEFF>
__device__ void gemm_small(const bf16* __restrict__ a, const bf16* __restrict__ pack,
                           float (* __restrict__ zbuf)[64][16], int w, int tid)
{
  const int lane = tid & 63, wid = tid >> 6;
  const int v = wid & 3, s = wid >> 2;
  const int lr = lane & 15, lq = lane >> 4;
  const int n0 = 16 * w;

  const bf16* wbase = pack + ((size_t)lq * NEFF + (n0 + lr)) * 8;

  bf16x8 wreg[8];
  #pragma unroll
  for (int i = 0; i < 8; ++i)
    wreg[i] = *(const bf16x8*)(wbase + (size_t)(s + 4 * i) * (4 * NEFF * 8));

  floatx4 c = {0.f,0.f,0.f,0.f};
  const bf16* ab = a + (size_t)(16 * v + lr) * NU;

  bf16x8 xa[2];
  xa[0] = *(const bf16x8*)(ab + s * 32 + lq * 8);
  #pragma unroll
  for (int i = 0; i < 8; ++i) {
    const int cur = i & 1, nxt = cur ^ 1;
    if (i + 1 < 8)
      xa[nxt] = *(const bf16x8*)(ab + (s + 4 * (i + 1)) * 32 + lq * 8);
    c = __builtin_amdgcn_mfma_f32_16x16x32_bf16(xa[cur], wreg[i], c, 0, 0, 0);
  }

  #pragma unroll
  for (int r = 0; r < 4; ++r) zbuf[s][16 * v + lq * 4 + r][lr] = c[r];
  __syncthreads();
}

extern "C" __global__ void __launch_bounds__(NTHR)
dancer_main(Params p)
{
  __shared__ __align__(16) char cbuf[16 * 8192];  // 128 KB: 16 waves x 4 slots x 2KB
  __shared__ float zbuf[4][64][16];               // 16 KB K-split / gemm exchange
  __shared__ bf16  hstage[64][16];                // 2 KB h staging
  cg::grid_group grid = cg::this_grid();
  const int tid = threadIdx.x;
  const int bid = blockIdx.x;
  // (r,w) decode; 4 row-sharers of a column share bid%8 -> same XCD L2
  const int m8 = bid & 7;
  const int q  = bid >> 3;
  const int r  = q & 3;
  const int w  = (q >> 2) * 8 + m8;
  const int R0 = 16 * r;
  const int gtid = bid * NTHR + tid;
  const int rmask = p.rmask, pmask = p.pmask;

  // per-thread c-state for the 6 LSTM layers (tid<256 <-> (m,u) fixed mapping)
  float cc0 = 0.f, cc1 = 0.f, cc2 = 0.f, cc3 = 0.f, cc4 = 0.f, cc5 = 0.f;

  // ---- init ----
  if (tid == 0) {
    p.arrv[bid * 32] = 0;
    if (bid == 0) *p.gof = 0;
  }
  for (int i = gtid; i < 6 * NB * NU; i += NWG * NTHR) {
    const int b = i >> 16, off = i & 65535;
    p.hr[b][(size_t)rmask * HSLOT + off] = (bf16)0.f;
  }
  for (int i = gtid; i < NB * YW; i += NWG * NTHR) {
    const int m = i / YW, c = i - m * YW;
    p.ybuf[i] = (c < NOUT) ? (bf16)p.curr[m * NOUT + c] : (bf16)0.f;
  }
  for (int i = gtid; i < (rmask + 1) * NB * 16; i += NWG * NTHR) {
    const int slot = i >> 10, m = (i >> 4) & 63, cix = i & 15;
    p.hbot[(size_t)slot * BSLOT + (size_t)m * BW + 512 + cix] = (bf16)0.f;
  }
  __syncthreads();
  grid.sync();   // full fence once: init writes visible everywhere

  uint32 sc = 1;
  for (int t = 0; t < NT; ++t) {
    const int st_ = t & rmask;
    const int sp_ = (t - 1) & rmask;
    __syncthreads();  // protect zbuf/hstage/cbuf reuse against previous readers

    // enc1: A = [audio_t (512) | h_enc1(t-1) (1024)], K=1536
    lstm_cell<NT * NDIM, NDIM, NU, NDIM, NU, NDIM + NU, NDIM + NU>(
        p.audio_bf + t * NDIM, p.hr[0] + (size_t)sp_ * HSLOT, p.hr[0] + (size_t)sp_ * HSLOT,
        p.pk[0], p.bias[0], p.hr[0] + (size_t)st_ * HSLOT, cc0, zbuf, &hstage[0],
        cbuf, w, R0, tid);
    gbar(p.arrv, sc++, bid, tid);

    lstm_cell<NU, NU, NU, NU, NU, 2 * NU, 2 * NU>(
        p.hr[0] + (size_t)st_ * HSLOT, p.hr[1] + (size_t)sp_ * HSLOT, p.hr[1] + (size_t)sp_ * HSLOT,
        p.pk[1], p.bias[1], p.hr[1] + (size_t)st_ * HSLOT, cc1, zbuf, &hstage[0],
        cbuf, w, R0, tid);
    gbar(p.arrv, sc++, bid, tid);

    lstm_cell<NU, NU, NU, NU, NU, 2 * NU, 2 * NU>(
        p.hr[1] + (size_t)st_ * HSLOT, p.hr[2] + (size_t)sp_ * HSLOT, p.hr[2] + (size_t)sp_ * HSLOT,
        p.pk[2], p.bias[2], p.hr[2] + (size_t)st_ * HSLOT, cc2, zbuf, &hstage[0],
        cbuf, w, R0, tid);
    gbar(p.arrv, sc++, bid, tid);

    // fc: _h = tanh(h_enc3 @ fc_W + b) -> hbot slot t (r==0 row group, w<32)
    if (r == 0 && w < 32) {
      gemm_small<512>(p.hr[2] + (size_t)st_ * HSLOT, p.pk[3], zbuf, w, tid);
      const int m = tid >> 4, u = tid & 15;
      const float z = zbuf[0][m][u] + zbuf[1][m][u] + zbuf[2][m][u] + zbuf[3][m][u]
                      + p.bias[3][16 * w + u];
      hstage[m][u] = (bf16)tanhf(z);
      __syncthreads();
      if (tid < 512) {
        const int m2 = tid >> 3, up = tid & 7;
        const uint32 v = *(const uint32*)&hstage[m2][2 * up];
        __hip_atomic_store((uint32*)(p.hbot + (size_t)st_ * BSLOT + (size_t)m2 * BW + 16 * w) + up,
                           v, __ATOMIC_RELAXED, __HIP_MEMORY_SCOPE_AGENT);
      }
    }
    gbar(p.arrv, sc++, bid, tid);

    // dec1: A = [ybuf(t) (80) | hbot(t) (528) | h_dec1(t-1) (1024)],
    // K padded 1632->1664; tail A clamped, tail B zero-packed
    lstm_cell<YW, YW, BW, YW + BW, NU, 1664, YW + BW + NU>(
        p.ybuf + (size_t)st_ * YSLOT, p.hbot + (size_t)st_ * BSLOT, p.hr[3] + (size_t)sp_ * HSLOT,
        p.pk[4], p.bias[4], p.hr[3] + (size_t)st_ * HSLOT, cc3, zbuf, &hstage[0],
        cbuf, w, R0, tid);
    gbar(p.arrv, sc++, bid, tid);

    lstm_cell<NU, NU, NU, NU, NU, 2 * NU, 2 * NU>(
        p.hr[3] + (size_t)st_ * HSLOT, p.hr[4] + (size_t)sp_ * HSLOT, p.hr[4] + (size_t)sp_ * HSLOT,
        p.pk[5], p.bias[5], p.hr[4] + (size_t)st_ * HSLOT, cc4, zbuf, &hstage[0],
        cbuf, w, R0, tid);
    gbar(p.arrv, sc++, bid, tid);

    lstm_cell<NU, NU, NU, NU, NU, 2 * NU, 2 * NU>(
        p.hr[4] + (size_t)st_ * HSLOT, p.hr[5] + (size_t)sp_ * HSLOT, p.hr[5] + (size_t)sp_ * HSLOT,
        p.pk[6], p.bias[6], p.hr[5] + (size_t)st_ * HSLOT, cc5, zbuf, &hstage[0],
        cbuf, w, R0, tid);
    gbar(p.arrv, sc++, bid, tid);

    // out: y = elu(h_dec3 @ out_W + b) -> d_out and ybuf slot t+1 (r==0, w<5;
    // no barrier: stores drain at next gbar, 4 barriers before dec1(t+1) reads)
    if (r == 0 && w < 5) {
      gemm_small<80>(p.hr[5] + (size_t)st_ * HSLOT, p.pk[7], zbuf, w, tid);
      const int m = tid >> 4, u = tid & 15;
      const int n = 16 * w + u;
      float y = 0.f;
      if (n < NOUT) {
        const float z = zbuf[0][m][u] + zbuf[1][m][u] + zbuf[2][m][u] + zbuf[3][m][u]
                        + p.bias[7][n];
        y = (z > 0.f) ? z : (__expf(z) - 1.f);
        p.out[(m * NT + t) * NOUT + n] = y;
      }
      hstage[m][u] = (bf16)y;
      __syncthreads();
      if (tid < 512) {
        const int m2 = tid >> 3, up = tid & 7;
        const uint32 v = *(const uint32*)&hstage[m2][2 * up];
        const size_t sn = (size_t)((t + 1) & rmask) * YSLOT;
        __hip_atomic_store((uint32*)(p.ybuf + sn + (size_t)m2 * YW + 16 * w) + up,
                           v, __ATOMIC_RELAXED, __HIP_MEMORY_SCOPE_AGENT);
      }
    }
    // periodic full sync: flush any cached ring lines before slot reuse
    if ((t & pmask) == pmask) grid.sync();
  }
}

// ---- pre-kernels ----

__global__ void pack_w(const float* __restrict__ Wx, const float* __restrict__ Wh,
                       int Kx, int KhStart, int Keff, int N, int Neff,
                       bf16* __restrict__ dst)
{
  const int idx = blockIdx.x * blockDim.x + threadIdx.x;
  const int nkb = Keff >> 3;
  const int total = nkb * Neff;
  if (idx >= total) return;
  const int kb = idx / Neff;
  const int n  = idx - kb * Neff;
  bf16x8 o;
  #pragma unroll
  for (int j = 0; j < 8; ++j) {
    const int k = kb * 8 + j;
    float v = 0.f;
    if (n < N) {
      if (k < Kx) v = Wx[(size_t)k * N + n];
      else if (k >= KhStart) v = Wh[(size_t)(k - KhStart) * N + n];
    }
    o[j] = (bf16)v;
  }
  *(bf16x8*)(dst + ((size_t)kb * Neff + n) * 8) = o;
}

// dec1: rows 0..74 = Wx[0..74] (y), 75..79 = 0, 80..591 = Wx[75..586] (_h),
//       592..607 = 0, 608..1631 = Wh, 1632..1663 = 0 (pad). K=1664, N=4096.
__global__ void pack_dec1(const float* __restrict__ Wx, const float* __restrict__ Wh,
                          bf16* __restrict__ dst)
{
  const int idx = blockIdx.x * blockDim.x + threadIdx.x;
  const int total = (1664 >> 3) * 4096;
  if (idx >= total) return;
  const int kb = idx >> 12;
  const int n  = idx & 4095;
  bf16x8 o;
  #pragma unroll
  for (int j = 0; j < 8; ++j) {
    const int k = kb * 8 + j;
    float v = 0.f;
    if (k < 75)                    v = Wx[(size_t)k * 4096 + n];
    else if (k >= 80 && k < 592)   v = Wx[(size_t)(k - 5) * 4096 + n];
    else if (k >= 608 && k < 1632) v = Wh[(size_t)(k - 608) * 4096 + n];
    o[j] = (bf16)v;
  }
  *(bf16x8*)(dst + ((size_t)kb * 4096 + n) * 8) = o;
}

__global__ void cvt_bf16(const float* __restrict__ src, bf16* __restrict__ dst, int n)
{
  const int i = blockIdx.x * blockDim.x + threadIdx.x;
  if (i < n) dst[i] = (bf16)src[i];
}

extern "C" void kernel_launch(void* const* d_in, const int* in_sizes, int n_in,
                              void* d_out, int out_size, void* d_ws, size_t ws_size,
                              hipStream_t stream)
{
  (void)in_sizes; (void)n_in; (void)out_size;

  const float* audio = (const float*)d_in[0];
  const float* curr  = (const float*)d_in[1];
  const float* Wp[8][2] = {
    { (const float*)d_in[2],  (const float*)d_in[3]  },  // enc1
    { (const float*)d_in[5],  (const float*)d_in[6]  },  // enc2
    { (const float*)d_in[8],  (const float*)d_in[9]  },  // enc3
    { (const float*)d_in[11], nullptr                },  // fc
    { (const float*)d_in[13], (const float*)d_in[14] },  // dec1
    { (const float*)d_in[16], (const float*)d_in[17] },  // dec2
    { (const float*)d_in[19], (const float*)d_in[20] },  // dec3
    { (const float*)d_in[22], nullptr                },  // out
  };
  const float* bias[8] = {
    (const float*)d_in[4],  (const float*)d_in[7],  (const float*)d_in[10],
    (const float*)d_in[12], (const float*)d_in[15], (const float*)d_in[18],
    (const float*)d_in[21], (const float*)d_in[23],
  };

  // {Kx, KhStart, Keff, N, Neff}; dec1 handled by pack_dec1 (K padded to 1664)
  const int geo[8][5] = {
    { 512,  512,  1536, 4096, 4096 },  // enc1
    { 1024, 1024, 2048, 4096, 4096 },  // enc2
    { 1024, 1024, 2048, 4096, 4096 },  // enc3
    { 1024, 1024, 1024, 512,  512  },  // fc
    { 0,    0,    1664, 4096, 4096 },  // dec1 (custom, padded)
    { 1024, 1024, 2048, 4096, 4096 },  // dec2
    { 1024, 1024, 2048, 4096, 4096 },  // dec3
    { 1024, 1024, 1024, 75,   80   },  // out
  };

  char* ws = (char*)d_ws;
  size_t off = 0;
  auto take = [&](size_t bytes) -> char* {
    char* p = ws + off;
    off = (off + bytes + 255) & ~(size_t)255;
    return p;
  };

  bf16* audio_bf = (bf16*)take((size_t)NB * NT * NDIM * 2);
  bf16* pk[8];
  for (int i = 0; i < 8; ++i) pk[i] = (bf16*)take((size_t)geo[i][2] * geo[i][4] * 2);
  uint32* arrv = (uint32*)take((size_t)NWG * 32 * sizeof(uint32));
  uint32* gof  = (uint32*)take(256);

  // pick ring depth that fits ws
  const size_t slot_bytes = (size_t)6 * HSLOT * 2 + (size_t)YSLOT * 2 + (size_t)BSLOT * 2 + 4096;
  int R = 32;
  while (R > 4 && off + (size_t)R * slot_bytes + (1 << 20) > ws_size) R >>= 1;

  bf16* hr[6];
  for (int i = 0; i < 6; ++i) hr[i] = (bf16*)take((size_t)R * HSLOT * 2);
  bf16* ybuf = (bf16*)take((size_t)R * YSLOT * 2);
  bf16* hbot = (bf16*)take((size_t)R * BSLOT * 2);

  {
    const int n = NB * NT * NDIM;
    cvt_bf16<<<(n + 255) / 256, 256, 0, stream>>>(audio, audio_bf, n);
  }
  for (int i = 0; i < 8; ++i) {
    if (i == 4) {
      const int total = (1664 >> 3) * 4096;
      pack_dec1<<<(total + 255) / 256, 256, 0, stream>>>(Wp[4][0], Wp[4][1], pk[4]);
    } else {
      const int total = (geo[i][2] >> 3) * geo[i][4];
      pack_w<<<(total + 255) / 256, 256, 0, stream>>>(
          Wp[i][0], Wp[i][1], geo[i][0], geo[i][1], geo[i][2], geo[i][3], geo[i][4], pk[i]);
    }
  }

  Params P;
  P.curr = curr;
  for (int i = 0; i < 8; ++i) { P.bias[i] = bias[i]; P.pk[i] = pk[i]; }
  P.audio_bf = audio_bf;
  for (int i = 0; i < 6; ++i) P.hr[i] = hr[i];
  P.ybuf = ybuf;
  P.hbot = hbot;
  P.arrv = arrv;
  P.gof = gof;
  P.out = (float*)d_out;
  P.rmask = R - 1;
  P.pmask = (R >> 1) - 1;

  void* args[] = { &P };
  (void)hipLaunchCooperativeKernel(reinterpret_cast<void*>(dancer_main),
                                   dim3(NWG), dim3(NTHR), args, 0, stream);
}